// Round 6
// baseline (5876.142 us; speedup 1.0000x reference)
//
#include <hip/hip_runtime.h>
#include <math.h>

typedef float f32;
typedef short short8 __attribute__((ext_vector_type(8)));
typedef float f32x4 __attribute__((ext_vector_type(4)));

#define TT 512
#define BB 64
#define DD 256
#define NN 48
#define LDA 264   // padded LDS row (shorts): 528B -> 2-way (free) bank aliasing

// ===== workspace offsets (bytes). Peak ~153.0 MB =====
static const size_t OFF_EBF  = 0;                        // [32000][256] bf16
static const size_t OFF_PXF  = 16384000;                 // [512][64][768] bf16
static const size_t OFF_PXB  = OFF_PXF + 50331648;
static const size_t OFF_HBF_F= OFF_PXB + 50331648;       // [512][64][256] bf16
static const size_t OFF_HBF_B= OFF_HBF_F + 16777216;
static const size_t OFF_WXTF = OFF_HBF_B + 16777216;     // [768][256] bf16
static const size_t OFF_WXTB = OFF_WXTF + 393216;
static const size_t OFF_WHTF = OFF_WXTB + 393216;        // [768][256] bf16 wh^T
static const size_t OFF_WHTB = OFF_WHTF + 393216;
static const size_t OFF_WQT  = OFF_WHTB + 393216;        // [256][512] bf16
static const size_t OFF_WKT  = OFF_WQT + 262144;
static const size_t OFF_WVT  = OFF_WKT + 262144;
static const size_t OFF_WTT  = OFF_WVT + 262144;         // [48][256] bf16
// end 152,985,600
// attn phase aliases the (dead) px arena [16,384,000 .. 117,047,296):
static const size_t OFF_QBF = OFF_PXF;                   // [64][512][256] bf16 (also ABF)
static const size_t OFF_KBF = OFF_QBF + 16777216;        // (also LG f32 after AV)
static const size_t OFF_VBF = OFF_KBF + 16777216;
static const size_t OFF_VT  = OFF_VBF + 16777216;        // [64][256][512] bf16
static const size_t OFF_SCB = OFF_VT  + 16777216;        // [64][512][512] bf16 (in-place SM)
static const size_t OFF_ABF = OFF_QBF;
static const size_t OFF_LG  = OFF_KBF;                   // [64][512][48] f32

__device__ __forceinline__ ushort f2bf(f32 f) {
  union { f32 f; unsigned u; } v; v.f = f;
  unsigned r = v.u + 0x7fffu + ((v.u >> 16) & 1u);   // RNE
  return (ushort)(r >> 16);
}
__device__ __forceinline__ f32 bf2f(ushort u) {
  union { unsigned u; f32 f; } v; v.u = ((unsigned)u) << 16; return v.f;
}
__device__ __forceinline__ f32 fsigmoid(f32 x) { return 1.f / (1.f + __expf(-x)); }
__device__ __forceinline__ f32 ftanh(f32 x) { return 1.f - 2.f / (__expf(2.f * x) + 1.f); }

// ---------------------------------------------------------------------------
// generic transpose+convert: in f32 [P][Q] -> out bf16 [Q][P], P = 1<<PL2
template <int PL2>
__global__ __launch_bounds__(256) void tconv_k(
    const f32* __restrict__ in, ushort* __restrict__ out, int total, int Q) {
  int o = blockIdx.x * 256 + threadIdx.x;
  if (o >= total) return;
  int q = o >> PL2, p = o & ((1 << PL2) - 1);
  out[o] = f2bf(in[(size_t)p * Q + q]);
}

// embed table f32 -> bf16
__global__ __launch_bounds__(256) void conv_embed_k(
    const f32* __restrict__ in, ushort* __restrict__ out, int n4) {
  int i = blockIdx.x * 256 + threadIdx.x;
  if (i >= n4) return;
  float4 v = ((const float4*)in)[i];
  ushort4 o;
  o.x = f2bf(v.x); o.y = f2bf(v.y); o.z = f2bf(v.z); o.w = f2bf(v.w);
  ((ushort4*)out)[i] = o;
}

// v transpose bf16: [64][512][256] -> [64][256][512]
__global__ __launch_bounds__(256) void tr_v_k(
    const ushort* __restrict__ in, ushort* __restrict__ out) {
  __shared__ ushort tile[32][33];
  int b = blockIdx.z;
  int s0 = blockIdx.x * 32, d0 = blockIdx.y * 32;
  int xc = threadIdx.x & 31, y0 = threadIdx.x >> 5;
  for (int yy = y0; yy < 32; yy += 8)
    tile[yy][xc] = in[((size_t)b * 512 + s0 + yy) * 256 + d0 + xc];
  __syncthreads();
  for (int yy = y0; yy < 32; yy += 8)
    out[((size_t)b * 256 + d0 + yy) * 512 + s0 + xc] = tile[xc][yy];
}

// ---------------------------------------------------------------------------
// bf16 MFMA GEMM: 128x128 block tile, BK=32, 256 thr (4 waves, 64x64 each).
enum { GM_PX = 0, GM_QKV = 1, GM_SC = 2, GM_AV = 3, GM_LG = 4 };

template <int MODE>
__global__ __launch_bounds__(256) void mgemm(
    const ushort* __restrict__ Aa, const ushort* __restrict__ Ab,
    const ushort* __restrict__ Bt,
    f32* __restrict__ Cf, ushort* __restrict__ Cb,
    const f32* __restrict__ bias, const int* __restrict__ xi,
    int Ndim, int K, int rev) {
  const int m0 = blockIdx.y * 128;
  const int n0 = blockIdx.x * 128;
  const int bz = blockIdx.z;
  const int tid = threadIdx.x;
  const int l = tid & 63, w = tid >> 6;
  const int wr = w >> 1, wc = w & 1;
  __shared__ __align__(16) short Al[128 * 40];
  __shared__ __align__(16) short Bl[128 * 40];
  f32x4 acc[4][4] = {};

  const int rowa = tid >> 1;
  const int kha = (tid & 1) * 16;
  const int rA = m0 + rowa;
  const ushort* aBase = nullptr;
  const ushort* aBase2 = nullptr;
  if constexpr (MODE == GM_PX) {
    int tg = rA >> 6, b = rA & 63;
    int ts = rev ? (511 - tg) : tg;
    aBase = Aa + (size_t)xi[b * 512 + ts] * 256;
  } else if constexpr (MODE == GM_QKV) {
    int bl = rA >> 9, t = rA & 511;
    aBase = Aa + ((size_t)(t * 64 + bl)) * 256;            // fwd half
    aBase2 = Ab + ((size_t)((511 - t) * 64 + bl)) * 256;   // bwd half
  } else if constexpr (MODE == GM_SC) {
    aBase = Aa + ((size_t)(bz * 512 + rA)) * 256;
  } else if constexpr (MODE == GM_AV) {
    aBase = Aa + ((size_t)(bz * 512 + rA)) * 512;
  } else {
    aBase = Aa + (size_t)rA * 256;
  }
  const int rowb = tid >> 1;
  const int khb = (tid & 1) * 16;
  int rowg = n0 + rowb;
  if constexpr (MODE == GM_SC) rowg += bz * 512;
  if constexpr (MODE == GM_AV) rowg += bz * 256;
  const ushort* bBase = Bt + (size_t)rowg * K;
  const bool bValid = (MODE != GM_LG) || (n0 + rowb < Ndim);

  for (int k0 = 0; k0 < K; k0 += 32) {
    {
      int kk = k0 + kha;
      const ushort* src;
      if constexpr (MODE == GM_QKV)
        src = (kk < 256) ? aBase + kk : aBase2 + (kk - 256);
      else
        src = aBase + kk;
      uint4 a0 = *(const uint4*)src;
      uint4 a1 = *(const uint4*)(src + 8);
      *(uint4*)&Al[rowa * 40 + kha] = a0;
      *(uint4*)&Al[rowa * 40 + kha + 8] = a1;
    }
    {
      uint4 v0 = make_uint4(0, 0, 0, 0), v1 = make_uint4(0, 0, 0, 0);
      if (bValid) {
        const ushort* src = bBase + k0 + khb;
        v0 = *(const uint4*)src;
        v1 = *(const uint4*)(src + 8);
      }
      *(uint4*)&Bl[rowb * 40 + khb] = v0;
      *(uint4*)&Bl[rowb * 40 + khb + 8] = v1;
    }
    __syncthreads();
    const int fr = l & 15, fg = l >> 4;
    short8 af[4], bfr[4];
#pragma unroll
    for (int mf = 0; mf < 4; ++mf)
      af[mf] = *(const short8*)&Al[(wr * 64 + mf * 16 + fr) * 40 + fg * 8];
#pragma unroll
    for (int nf = 0; nf < 4; ++nf)
      bfr[nf] = *(const short8*)&Bl[(wc * 64 + nf * 16 + fr) * 40 + fg * 8];
#pragma unroll
    for (int mf = 0; mf < 4; ++mf)
#pragma unroll
      for (int nf = 0; nf < 4; ++nf)
        acc[mf][nf] = __builtin_amdgcn_mfma_f32_16x16x32_bf16(
            af[mf], bfr[nf], acc[mf][nf], 0, 0, 0);
    __syncthreads();
  }

  const int fr = l & 15, fq = l >> 4;
#pragma unroll
  for (int mf = 0; mf < 4; ++mf) {
#pragma unroll
    for (int nf = 0; nf < 4; ++nf) {
      int col = n0 + wc * 64 + nf * 16 + fr;
      f32 bs = 0.f;
      if (bias && col < Ndim) bs = bias[col];
#pragma unroll
      for (int rg = 0; rg < 4; ++rg) {
        int row = m0 + wr * 64 + mf * 16 + fq * 4 + rg;
        f32 vv = acc[mf][nf][rg] + bs;
        if constexpr (MODE == GM_PX)
          Cb[(size_t)row * 768 + col] = f2bf(vv);
        else if constexpr (MODE == GM_QKV)
          Cb[(size_t)row * 256 + col] = f2bf(vv);
        else if constexpr (MODE == GM_SC)
          Cb[((size_t)bz * 512 + row) * 512 + col] = f2bf(vv);
        else if constexpr (MODE == GM_AV)
          Cb[((size_t)bz * 512 + row) * 256 + col] = f2bf(vv);
        else {
          if (col < Ndim) Cf[(size_t)row * 48 + col] = vv;
        }
      }
    }
  }
}

// ---------------------------------------------------------------------------
// GRU scan, row-partitioned: 8 WGs = 2 dir x 4 row-groups (16 batch rows).
// Zero inter-WG communication. z/r weights VGPR-resident (MFMA B-fragments),
// h-gate weights + h double-buffer in LDS (padded rows, conflict-free).
__global__ __launch_bounds__(256, 1) void gru_scan3(
    const ushort* __restrict__ pxf, const ushort* __restrict__ pxb,
    const ushort* __restrict__ whtf, const ushort* __restrict__ whtb,
    const f32* __restrict__ b_f, const f32* __restrict__ b_b,
    ushort* __restrict__ hfbf, ushort* __restrict__ hbbf) {
  const int dir = blockIdx.x >> 2;
  const int rg  = blockIdx.x & 3;           // batch rows rg*16 .. +15
  const int tid = threadIdx.x;
  const int w = tid >> 6, l = tid & 63;
  const int fr = l & 15, fg = l >> 4;       // fragment row/col & k-group
  const ushort* px  = dir ? pxb : pxf;
  const ushort* wht = dir ? whtb : whtf;
  const f32* bh = (dir ? b_b : b_f) + 768;
  ushort* hseq = dir ? hbbf : hfbf;

  __shared__ __align__(16) short ldsW[256 * LDA];   // h-gate W^T [256 cols][256 k]
  __shared__ __align__(16) short hbuf[2][16 * LDA]; // h [16 rows][256 cols] x2

  // stage Wh slab (gate rows 512..767), 16B chunks
  for (int i = tid; i < 256 * 32; i += 256) {
    int row = i >> 5, ch = i & 31;
    uint4 v = *(const uint4*)&wht[(size_t)(512 + row) * 256 + ch * 8];
    *(uint4*)&ldsW[row * LDA + ch * 8] = v;
  }
  // zero h0 (both buffers' first is enough; zero buf0)
  for (int i = tid; i < 16 * LDA / 2; i += 256) ((uint*)hbuf[0])[i] = 0u;

  const int colw = w * 64;                  // wave's h-col base
  // z/r weight fragments -> VGPRs (2 gates x 4 col-tiles x 8 k-slices)
  short8 wz[4][8], wrg[4][8];
#pragma unroll
  for (int ct = 0; ct < 4; ++ct) {
    int colz = colw + ct * 16 + fr;
#pragma unroll
    for (int ks = 0; ks < 8; ++ks) {
      wz[ct][ks]  = *(const short8*)&wht[(size_t)colz * 256 + ks * 32 + fg * 8];
      wrg[ct][ks] = *(const short8*)&wht[(size_t)(256 + colz) * 256 + ks * 32 + fg * 8];
    }
  }
  f32 bhz[4], bhr[4], bhh[4];
#pragma unroll
  for (int ct = 0; ct < 4; ++ct) {
    int colg = colw + ct * 16 + fr;
    bhz[ct] = bh[colg]; bhr[ct] = bh[256 + colg]; bhh[ct] = bh[512 + colg];
  }
  f32 hold[16];
#pragma unroll
  for (int i = 0; i < 16; ++i) hold[i] = 0.f;
  __syncthreads();

  int cur = 0;
#pragma unroll 1
  for (int t = 0; t < TT; ++t) {
    // px prefetch (48 scalars; consumed after MFMA -> latency hidden)
    ushort pz[16], pr_[16], ph[16];
    {
      const ushort* pxt = px + ((size_t)t * 64 + rg * 16) * 768;
#pragma unroll
      for (int ct = 0; ct < 4; ++ct)
#pragma unroll
        for (int ri = 0; ri < 4; ++ri) {
          const ushort* p = pxt + (fg * 4 + ri) * 768 + colw + ct * 16 + fr;
          pz[ct * 4 + ri] = p[0];
          pr_[ct * 4 + ri] = p[256];
          ph[ct * 4 + ri] = p[512];
        }
    }
    // A fragments: h_t [16 rows][256 k]
    short8 a[8];
#pragma unroll
    for (int ks = 0; ks < 8; ++ks)
      a[ks] = *(const short8*)&hbuf[cur][fr * LDA + ks * 32 + fg * 8];
    // MFMA: 3 gates x 4 col-tiles, k=256
    f32x4 az[4] = {}, ar[4] = {}, ah[4] = {};
#pragma unroll
    for (int ks = 0; ks < 8; ++ks) {
#pragma unroll
      for (int ct = 0; ct < 4; ++ct) {
        az[ct] = __builtin_amdgcn_mfma_f32_16x16x32_bf16(a[ks], wz[ct][ks], az[ct], 0, 0, 0);
        ar[ct] = __builtin_amdgcn_mfma_f32_16x16x32_bf16(a[ks], wrg[ct][ks], ar[ct], 0, 0, 0);
        short8 wh8 = *(const short8*)&ldsW[(colw + ct * 16 + fr) * LDA + ks * 32 + fg * 8];
        ah[ct] = __builtin_amdgcn_mfma_f32_16x16x32_bf16(a[ks], wh8, ah[ct], 0, 0, 0);
      }
    }
    // gates; carry in f32 regs; publish h to LDS (next step) + global (bf16)
#pragma unroll
    for (int ct = 0; ct < 4; ++ct)
#pragma unroll
      for (int ri = 0; ri < 4; ++ri) {
        int idx = ct * 4 + ri;
        int lr = fg * 4 + ri;
        int col = colw + ct * 16 + fr;
        f32 zv = fsigmoid(az[ct][ri] + bhz[ct] + bf2f(pz[idx]));
        f32 rv = fsigmoid(ar[ct][ri] + bhr[ct] + bf2f(pr_[idx]));
        f32 hc = ftanh(bf2f(ph[idx]) + rv * (ah[ct][ri] + bhh[ct]));
        f32 hn = zv * hold[idx] + (1.f - zv) * hc;
        hold[idx] = hn;
        ushort hb = f2bf(hn);
        hbuf[cur ^ 1][lr * LDA + col] = (short)hb;
        hseq[((size_t)t * 64 + rg * 16 + lr) * 256 + col] = hb;
      }
    __syncthreads();
    cur ^= 1;
  }
}

// ---------------------------------------------------------------------------
// in-place row softmax over 512 bf16, one block per row
__global__ __launch_bounds__(256) void softmax_ip(ushort* __restrict__ p) {
  size_t row = blockIdx.x;
  uint* pr = (uint*)(p + row * 512);
  int tid = threadIdx.x;
  uint u = pr[tid];
  f32 v0 = bf2f((ushort)(u & 0xffff)), v1 = bf2f((ushort)(u >> 16));
  f32 m = fmaxf(v0, v1);
  for (int off = 32; off; off >>= 1) m = fmaxf(m, __shfl_xor(m, off));
  __shared__ f32 red[4];
  __shared__ f32 red2[4];
  if ((tid & 63) == 0) red[tid >> 6] = m;
  __syncthreads();
  m = fmaxf(fmaxf(red[0], red[1]), fmaxf(red[2], red[3]));
  f32 e0 = __expf(v0 - m), e1 = __expf(v1 - m);
  f32 s = e0 + e1;
  for (int off = 32; off; off >>= 1) s += __shfl_xor(s, off);
  if ((tid & 63) == 0) red2[tid >> 6] = s;
  __syncthreads();
  s = red2[0] + red2[1] + red2[2] + red2[3];
  f32 inv = 1.f / s;
  pr[tid] = (uint)f2bf(e0 * inv) | ((uint)f2bf(e1 * inv) << 16);
}

// ---------------------------------------------------------------------------
// CRF log-likelihood, one block (1 wave) per batch element
__global__ __launch_bounds__(64) void crf_ll_k(
    const f32* __restrict__ logits, const int* __restrict__ y,
    const int* __restrict__ seq_len, const f32* __restrict__ trans,
    f32* __restrict__ out) {
  const int b = blockIdx.x, tid = threadIdx.x;
  __shared__ f32 tr[NN][NN];
  __shared__ f32 al[2][NN];
  for (int i = tid; i < NN * NN; i += 64) tr[i / NN][i % NN] = trans[i];
  const f32* em = logits + (size_t)b * TT * NN;
  const int L = seq_len[b];
  if (tid < NN) al[0][tid] = em[tid];
  __syncthreads();
  int cur = 0;
  for (int t = 1; t < TT; ++t) {
    if (t >= L) break;
    if (tid < NN) {
      f32 m = -1e30f;
      for (int i = 0; i < NN; ++i) m = fmaxf(m, al[cur][i] + tr[i][tid]);
      f32 s = 0.f;
      for (int i = 0; i < NN; ++i) s += __expf(al[cur][i] + tr[i][tid] - m);
      al[cur ^ 1][tid] = m + __logf(s) + em[t * NN + tid];
    }
    __syncthreads();
    cur ^= 1;
  }
  f32 us = 0.f, ts = 0.f;
  for (int t = tid; t < TT; t += 64) {
    if (t < L) {
      us += em[t * NN + y[b * TT + t]];
      if (t >= 1) ts += tr[y[b * TT + t - 1]][y[b * TT + t]];
    }
  }
  for (int off = 32; off; off >>= 1) { us += __shfl_xor(us, off); ts += __shfl_xor(ts, off); }
  if (tid == 0) {
    f32 m = -1e30f;
    for (int i = 0; i < NN; ++i) m = fmaxf(m, al[cur][i]);
    f32 s = 0.f;
    for (int i = 0; i < NN; ++i) s += __expf(al[cur][i] - m);
    out[(size_t)BB * TT + b] = us + ts - (m + __logf(s));
  }
}

// CRF Viterbi decode, one block (1 wave) per batch element
__global__ __launch_bounds__(64) void crf_decode_k(
    const f32* __restrict__ logits, const int* __restrict__ seq_len,
    const f32* __restrict__ trans, f32* __restrict__ out) {
  const int b = blockIdx.x, tid = threadIdx.x;
  __shared__ f32 tr[NN][NN];
  __shared__ f32 al[2][NN];
  __shared__ unsigned char bp[TT - 1][NN];
  __shared__ unsigned char pr[TT];
  for (int i = tid; i < NN * NN; i += 64) tr[i / NN][i % NN] = trans[i];
  const f32* em = logits + (size_t)b * TT * NN;
  const int L = seq_len[b];
  if (tid < NN) al[0][tid] = em[tid];
  __syncthreads();
  int cur = 0;
  for (int t = 1; t < TT; ++t) {
    if (tid < NN) {
      if (t < L) {
        f32 m = -1e30f; int arg = 0;
        for (int i = 0; i < NN; ++i) {
          f32 v = al[cur][i] + tr[i][tid];
          if (v > m) { m = v; arg = i; }
        }
        al[cur ^ 1][tid] = m + em[t * NN + tid];
        bp[t - 1][tid] = (unsigned char)arg;
      } else {
        al[cur ^ 1][tid] = al[cur][tid];
        bp[t - 1][tid] = (unsigned char)tid;
      }
    }
    __syncthreads();
    cur ^= 1;
  }
  if (tid == 0) {
    f32 m = -1e30f; int last = 0;
    for (int i = 0; i < NN; ++i)
      if (al[cur][i] > m) { m = al[cur][i]; last = i; }
    int tag = last;
    for (int t = TT - 2; t >= 0; --t) { pr[t + 1] = (unsigned char)tag; tag = bp[t][tag]; }
    pr[0] = (unsigned char)tag;
  }
  __syncthreads();
  for (int t = tid; t < TT; t += 64)
    out[(size_t)b * TT + t] = (f32)pr[t];
}

// ---------------------------------------------------------------------------
extern "C" void kernel_launch(void* const* d_in, const int* in_sizes, int n_in,
                              void* d_out, int out_size, void* d_ws, size_t ws_size,
                              hipStream_t stream) {
  const int* x       = (const int*)d_in[0];
  const int* y       = (const int*)d_in[1];
  const int* seq_len = (const int*)d_in[2];
  const f32* embed   = (const f32*)d_in[3];
  const f32* wx_f    = (const f32*)d_in[4];
  const f32* wh_f    = (const f32*)d_in[5];
  const f32* b_f     = (const f32*)d_in[6];
  const f32* wx_b    = (const f32*)d_in[7];
  const f32* wh_b    = (const f32*)d_in[8];
  const f32* b_b     = (const f32*)d_in[9];
  const f32* wq      = (const f32*)d_in[10];
  const f32* bq      = (const f32*)d_in[11];
  const f32* wk      = (const f32*)d_in[12];
  const f32* bk      = (const f32*)d_in[13];
  const f32* wv      = (const f32*)d_in[14];
  const f32* bv      = (const f32*)d_in[15];
  const f32* wt      = (const f32*)d_in[16];
  const f32* bt      = (const f32*)d_in[17];
  const f32* trans   = (const f32*)d_in[18];
  f32* out = (f32*)d_out;

  char* ws = (char*)d_ws;
  ushort* ebf  = (ushort*)(ws + OFF_EBF);
  ushort* pxfb = (ushort*)(ws + OFF_PXF);
  ushort* pxbb = (ushort*)(ws + OFF_PXB);
  ushort* hfbf = (ushort*)(ws + OFF_HBF_F);
  ushort* hbbf = (ushort*)(ws + OFF_HBF_B);
  ushort* wxtf = (ushort*)(ws + OFF_WXTF);
  ushort* wxtb = (ushort*)(ws + OFF_WXTB);
  ushort* whtf = (ushort*)(ws + OFF_WHTF);
  ushort* whtb = (ushort*)(ws + OFF_WHTB);
  ushort* wqt  = (ushort*)(ws + OFF_WQT);
  ushort* wkt  = (ushort*)(ws + OFF_WKT);
  ushort* wvt  = (ushort*)(ws + OFF_WVT);
  ushort* wtt  = (ushort*)(ws + OFF_WTT);
  ushort* qbf = (ushort*)(ws + OFF_QBF);
  ushort* kbf = (ushort*)(ws + OFF_KBF);
  ushort* vbf = (ushort*)(ws + OFF_VBF);
  ushort* vT  = (ushort*)(ws + OFF_VT);
  ushort* scb = (ushort*)(ws + OFF_SCB);
  ushort* abf = (ushort*)(ws + OFF_ABF);
  f32*    lg  = (f32*)(ws + OFF_LG);

  // ---- setup converts ----
  conv_embed_k<<<8000, 256, 0, stream>>>(embed, ebf, 2048000);
  tconv_k<8><<<768, 256, 0, stream>>>(wx_f, wxtf, 196608, 768);
  tconv_k<8><<<768, 256, 0, stream>>>(wx_b, wxtb, 196608, 768);
  tconv_k<8><<<768, 256, 0, stream>>>(wh_f, whtf, 196608, 768);
  tconv_k<8><<<768, 256, 0, stream>>>(wh_b, whtb, 196608, 768);
  tconv_k<9><<<512, 256, 0, stream>>>(wq, wqt, 131072, 256);
  tconv_k<9><<<512, 256, 0, stream>>>(wk, wkt, 131072, 256);
  tconv_k<9><<<512, 256, 0, stream>>>(wv, wvt, 131072, 256);
  tconv_k<8><<<48, 256, 0, stream>>>(wt, wtt, 12288, 48);

  // ---- px (both dirs), then row-partitioned MFMA scan (no inter-WG sync) ----
  mgemm<GM_PX><<<dim3(6, 256), 256, 0, stream>>>(
      ebf, nullptr, wxtf, nullptr, pxfb, b_f, x, 768, 256, 0);
  mgemm<GM_PX><<<dim3(6, 256), 256, 0, stream>>>(
      ebf, nullptr, wxtb, nullptr, pxbb, b_b, x, 768, 256, 1);
  gru_scan3<<<8, 256, 0, stream>>>(pxfb, pxbb, whtf, whtb, b_f, b_b, hfbf, hbbf);

  // ---- attention + logits, single pass over all 64 batches ----
  mgemm<GM_QKV><<<dim3(2, 256), 256, 0, stream>>>(
      hfbf, hbbf, wqt, nullptr, qbf, bq, nullptr, 256, 512, 0);
  mgemm<GM_QKV><<<dim3(2, 256), 256, 0, stream>>>(
      hfbf, hbbf, wkt, nullptr, kbf, bk, nullptr, 256, 512, 0);
  mgemm<GM_QKV><<<dim3(2, 256), 256, 0, stream>>>(
      hfbf, hbbf, wvt, nullptr, vbf, bv, nullptr, 256, 512, 0);
  tr_v_k<<<dim3(16, 8, 64), 256, 0, stream>>>(vbf, vT);
  mgemm<GM_SC><<<dim3(4, 4, 64), 256, 0, stream>>>(
      qbf, nullptr, kbf, nullptr, scb, nullptr, nullptr, 512, 256, 0);
  softmax_ip<<<BB * TT, 256, 0, stream>>>(scb);
  mgemm<GM_AV><<<dim3(2, 4, 64), 256, 0, stream>>>(
      scb, nullptr, vT, nullptr, abf, nullptr, nullptr, 256, 512, 0);
  mgemm<GM_LG><<<dim3(1, 256), 256, 0, stream>>>(
      abf, nullptr, wtt, lg, nullptr, bt, nullptr, 48, 256, 0);

  // ---- CRF ----
  crf_ll_k<<<BB, 64, 0, stream>>>(lg, y, seq_len, trans, out);
  crf_decode_k<<<BB, 64, 0, stream>>>(lg, seq_len, trans, out);
}

// Round 7
// 2903.222 us; speedup vs baseline: 2.0240x; 2.0240x over previous
//
#include <hip/hip_runtime.h>
#include <math.h>

typedef float f32;
typedef short short8 __attribute__((ext_vector_type(8)));
typedef float f32x4 __attribute__((ext_vector_type(4)));

#define TT 512
#define BB 64
#define DD 256
#define NN 48

// ===== workspace offsets (bytes). Peak ~153.0 MB =====
static const size_t OFF_EBF  = 0;                        // [32000][256] bf16
static const size_t OFF_PXF  = 16384000;                 // [512][64][768] bf16
static const size_t OFF_PXB  = OFF_PXF + 50331648;
static const size_t OFF_HBF_F= OFF_PXB + 50331648;       // [512][64][256] bf16
static const size_t OFF_HBF_B= OFF_HBF_F + 16777216;
static const size_t OFF_WXTF = OFF_HBF_B + 16777216;     // [768][256] bf16
static const size_t OFF_WXTB = OFF_WXTF + 393216;
static const size_t OFF_WHTF = OFF_WXTB + 393216;        // [768][256] bf16 wh^T
static const size_t OFF_WHTB = OFF_WHTF + 393216;
static const size_t OFF_WQT  = OFF_WHTB + 393216;        // [256][512] bf16
static const size_t OFF_WKT  = OFF_WQT + 262144;
static const size_t OFF_WVT  = OFF_WKT + 262144;
static const size_t OFF_WTT  = OFF_WVT + 262144;         // [48][256] bf16
// end 152,985,600
// attn phase aliases the (dead) px arena [16,384,000 .. 117,047,296):
static const size_t OFF_QBF = OFF_PXF;                   // [64][512][256] bf16 (also ABF)
static const size_t OFF_KBF = OFF_QBF + 16777216;        // (also LG f32 after AV)
static const size_t OFF_VBF = OFF_KBF + 16777216;
static const size_t OFF_VT  = OFF_VBF + 16777216;        // [64][256][512] bf16
static const size_t OFF_SCB = OFF_VT  + 16777216;        // [64][512][512] bf16 (in-place SM)
static const size_t OFF_ABF = OFF_QBF;
static const size_t OFF_LG  = OFF_KBF;                   // [64][512][48] f32

__device__ __forceinline__ ushort f2bf(f32 f) {
  union { f32 f; unsigned u; } v; v.f = f;
  unsigned r = v.u + 0x7fffu + ((v.u >> 16) & 1u);   // RNE
  return (ushort)(r >> 16);
}
__device__ __forceinline__ f32 bf2f(ushort u) {
  union { unsigned u; f32 f; } v; v.u = ((unsigned)u) << 16; return v.f;
}
__device__ __forceinline__ f32 fsigmoid(f32 x) { return 1.f / (1.f + __expf(-x)); }
__device__ __forceinline__ f32 ftanh(f32 x) { return 1.f - 2.f / (__expf(2.f * x) + 1.f); }

// ---------------------------------------------------------------------------
// generic transpose+convert: in f32 [P][Q] -> out bf16 [Q][P], P = 1<<PL2
template <int PL2>
__global__ __launch_bounds__(256) void tconv_k(
    const f32* __restrict__ in, ushort* __restrict__ out, int total, int Q) {
  int o = blockIdx.x * 256 + threadIdx.x;
  if (o >= total) return;
  int q = o >> PL2, p = o & ((1 << PL2) - 1);
  out[o] = f2bf(in[(size_t)p * Q + q]);
}

// embed table f32 -> bf16
__global__ __launch_bounds__(256) void conv_embed_k(
    const f32* __restrict__ in, ushort* __restrict__ out, int n4) {
  int i = blockIdx.x * 256 + threadIdx.x;
  if (i >= n4) return;
  float4 v = ((const float4*)in)[i];
  ushort4 o;
  o.x = f2bf(v.x); o.y = f2bf(v.y); o.z = f2bf(v.z); o.w = f2bf(v.w);
  ((ushort4*)out)[i] = o;
}

// v transpose bf16: [64][512][256] -> [64][256][512]
__global__ __launch_bounds__(256) void tr_v_k(
    const ushort* __restrict__ in, ushort* __restrict__ out) {
  __shared__ ushort tile[32][33];
  int b = blockIdx.z;
  int s0 = blockIdx.x * 32, d0 = blockIdx.y * 32;
  int xc = threadIdx.x & 31, y0 = threadIdx.x >> 5;
  for (int yy = y0; yy < 32; yy += 8)
    tile[yy][xc] = in[((size_t)b * 512 + s0 + yy) * 256 + d0 + xc];
  __syncthreads();
  for (int yy = y0; yy < 32; yy += 8)
    out[((size_t)b * 256 + d0 + yy) * 512 + s0 + xc] = tile[xc][yy];
}

// ---------------------------------------------------------------------------
// bf16 MFMA GEMM: 128x128 block tile, BK=32, 256 thr (4 waves, 64x64 each).
enum { GM_PX = 0, GM_QKV = 1, GM_SC = 2, GM_AV = 3, GM_LG = 4 };

template <int MODE>
__global__ __launch_bounds__(256) void mgemm(
    const ushort* __restrict__ Aa, const ushort* __restrict__ Ab,
    const ushort* __restrict__ Bt,
    f32* __restrict__ Cf, ushort* __restrict__ Cb,
    const f32* __restrict__ bias, const int* __restrict__ xi,
    int Ndim, int K, int rev) {
  const int m0 = blockIdx.y * 128;
  const int n0 = blockIdx.x * 128;
  const int bz = blockIdx.z;
  const int tid = threadIdx.x;
  const int l = tid & 63, w = tid >> 6;
  const int wr = w >> 1, wc = w & 1;
  __shared__ __align__(16) short Al[128 * 40];
  __shared__ __align__(16) short Bl[128 * 40];
  f32x4 acc[4][4] = {};

  const int rowa = tid >> 1;
  const int kha = (tid & 1) * 16;
  const int rA = m0 + rowa;
  const ushort* aBase = nullptr;
  const ushort* aBase2 = nullptr;
  if constexpr (MODE == GM_PX) {
    int tg = rA >> 6, b = rA & 63;
    int ts = rev ? (511 - tg) : tg;
    aBase = Aa + (size_t)xi[b * 512 + ts] * 256;
  } else if constexpr (MODE == GM_QKV) {
    int bl = rA >> 9, t = rA & 511;
    aBase = Aa + ((size_t)(t * 64 + bl)) * 256;            // fwd half
    aBase2 = Ab + ((size_t)((511 - t) * 64 + bl)) * 256;   // bwd half
  } else if constexpr (MODE == GM_SC) {
    aBase = Aa + ((size_t)(bz * 512 + rA)) * 256;
  } else if constexpr (MODE == GM_AV) {
    aBase = Aa + ((size_t)(bz * 512 + rA)) * 512;
  } else {
    aBase = Aa + (size_t)rA * 256;
  }
  const int rowb = tid >> 1;
  const int khb = (tid & 1) * 16;
  int rowg = n0 + rowb;
  if constexpr (MODE == GM_SC) rowg += bz * 512;
  if constexpr (MODE == GM_AV) rowg += bz * 256;
  const ushort* bBase = Bt + (size_t)rowg * K;
  const bool bValid = (MODE != GM_LG) || (n0 + rowb < Ndim);

  for (int k0 = 0; k0 < K; k0 += 32) {
    {
      int kk = k0 + kha;
      const ushort* src;
      if constexpr (MODE == GM_QKV)
        src = (kk < 256) ? aBase + kk : aBase2 + (kk - 256);
      else
        src = aBase + kk;
      uint4 a0 = *(const uint4*)src;
      uint4 a1 = *(const uint4*)(src + 8);
      *(uint4*)&Al[rowa * 40 + kha] = a0;
      *(uint4*)&Al[rowa * 40 + kha + 8] = a1;
    }
    {
      uint4 v0 = make_uint4(0, 0, 0, 0), v1 = make_uint4(0, 0, 0, 0);
      if (bValid) {
        const ushort* src = bBase + k0 + khb;
        v0 = *(const uint4*)src;
        v1 = *(const uint4*)(src + 8);
      }
      *(uint4*)&Bl[rowb * 40 + khb] = v0;
      *(uint4*)&Bl[rowb * 40 + khb + 8] = v1;
    }
    __syncthreads();
    const int fr = l & 15, fg = l >> 4;
    short8 af[4], bfr[4];
#pragma unroll
    for (int mf = 0; mf < 4; ++mf)
      af[mf] = *(const short8*)&Al[(wr * 64 + mf * 16 + fr) * 40 + fg * 8];
#pragma unroll
    for (int nf = 0; nf < 4; ++nf)
      bfr[nf] = *(const short8*)&Bl[(wc * 64 + nf * 16 + fr) * 40 + fg * 8];
#pragma unroll
    for (int mf = 0; mf < 4; ++mf)
#pragma unroll
      for (int nf = 0; nf < 4; ++nf)
        acc[mf][nf] = __builtin_amdgcn_mfma_f32_16x16x32_bf16(
            af[mf], bfr[nf], acc[mf][nf], 0, 0, 0);
    __syncthreads();
  }

  const int fr = l & 15, fq = l >> 4;
#pragma unroll
  for (int mf = 0; mf < 4; ++mf) {
#pragma unroll
    for (int nf = 0; nf < 4; ++nf) {
      int col = n0 + wc * 64 + nf * 16 + fr;
      f32 bs = 0.f;
      if (bias && col < Ndim) bs = bias[col];
#pragma unroll
      for (int rg = 0; rg < 4; ++rg) {
        int row = m0 + wr * 64 + mf * 16 + fq * 4 + rg;
        f32 vv = acc[mf][nf][rg] + bs;
        if constexpr (MODE == GM_PX)
          Cb[(size_t)row * 768 + col] = f2bf(vv);
        else if constexpr (MODE == GM_QKV)
          Cb[(size_t)row * 256 + col] = f2bf(vv);
        else if constexpr (MODE == GM_SC)
          Cb[((size_t)bz * 512 + row) * 512 + col] = f2bf(vv);
        else if constexpr (MODE == GM_AV)
          Cb[((size_t)bz * 512 + row) * 256 + col] = f2bf(vv);
        else {
          if (col < Ndim) Cf[(size_t)row * 48 + col] = vv;
        }
      }
    }
  }
}

// ---------------------------------------------------------------------------
// GRU scan v4: 8 WGs = 2 dir x 4 row-groups (16 rows), 512 threads (8 waves).
// Wave w owns 32 h-cols (col-tiles 2w, 2w+1), all 3 gates in-wave:
//   z/r weights VGPR-resident (128 regs/wave), h-gate weights in LDS
//   (XOR-swizzled, conflict-reduced). f32 carry in registers. Coalesced
//   cooperative hseq store. Zero inter-WG communication.
__global__ __launch_bounds__(512, 1) void gru_scan4(
    const ushort* __restrict__ pxf, const ushort* __restrict__ pxb,
    const ushort* __restrict__ whtf, const ushort* __restrict__ whtb,
    const f32* __restrict__ b_f, const f32* __restrict__ b_b,
    ushort* __restrict__ hfbf, ushort* __restrict__ hbbf) {
  const int dir = blockIdx.x >> 2;
  const int rg4 = blockIdx.x & 3;           // rows rg4*16 .. +15
  const int tid = threadIdx.x;
  const int w = tid >> 6, l = tid & 63;
  const int fr = l & 15, fq = l >> 4;       // fragment row/col, k-group
  const ushort* px  = dir ? pxb : pxf;
  const ushort* wht = dir ? whtb : whtf;
  const f32* bh = (dir ? b_b : b_f) + 768;
  ushort* hseq = dir ? hbbf : hfbf;

  __shared__ __align__(16) char ldsWh[131072];  // h-gate W^T [256 col][256 k] swz
  __shared__ __align__(16) char ldsH[8192];     // h [16 r][256 k] bf16 swz

  // ---- stage Wh (gate rows 512..767): 8192 x uint4, XOR-swizzled ----
#pragma unroll
  for (int i = 0; i < 16; ++i) {
    int idx = i * 512 + tid;                // 0..8191
    int col = idx >> 5, kc = idx & 31;      // col 0..255, 16B chunk 0..31
    uint4 v = *(const uint4*)&wht[(size_t)(512 + col) * 256 + kc * 8];
    *(uint4*)&ldsWh[col * 512 + ((kc * 16) ^ ((col & 7) << 4))] = v;
  }
  // zero h0
  for (int i = tid; i < 512; i += 512) ((uint4*)ldsH)[i] = make_uint4(0, 0, 0, 0);

  const int ctb = w * 2;                    // wave's col-tile base
  // ---- z/r weight fragments -> VGPRs: 2 gates x 2 ct x 8 ks = 128 regs ----
  short8 wzv[2][8], wrv[2][8];
#pragma unroll
  for (int ct = 0; ct < 2; ++ct) {
    int col = (ctb + ct) * 16 + fr;
#pragma unroll
    for (int ks = 0; ks < 8; ++ks) {
      wzv[ct][ks] = *(const short8*)&wht[(size_t)col * 256 + ks * 32 + fq * 8];
      wrv[ct][ks] = *(const short8*)&wht[(size_t)(256 + col) * 256 + ks * 32 + fq * 8];
    }
  }
  f32 bhz[2], bhr[2], bhh[2];
#pragma unroll
  for (int ct = 0; ct < 2; ++ct) {
    int col = (ctb + ct) * 16 + fr;
    bhz[ct] = bh[col]; bhr[ct] = bh[256 + col]; bhh[ct] = bh[512 + col];
  }
  f32 hold[8];
#pragma unroll
  for (int i = 0; i < 8; ++i) hold[i] = 0.f;
  __syncthreads();

#pragma unroll 1
  for (int t = 0; t < TT; ++t) {
    // ---- px loads (global; issued before MFMA -> latency hidden) ----
    ushort pz[8], pr_[8], ph[8];
    {
      const ushort* pxt = px + ((size_t)t * 64 + rg4 * 16) * 768;
#pragma unroll
      for (int ct = 0; ct < 2; ++ct) {
        int col = (ctb + ct) * 16 + fr;
#pragma unroll
        for (int ri = 0; ri < 4; ++ri) {
          const ushort* p = pxt + (fq * 4 + ri) * 768 + col;
          pz[ct * 4 + ri] = p[0];
          pr_[ct * 4 + ri] = p[256];
          ph[ct * 4 + ri] = p[512];
        }
      }
    }
    // ---- MFMA: 3 gates x 2 col-tiles, k=256; A streamed from ldsH ----
    f32x4 az[2] = {}, ar[2] = {}, ah[2] = {};
#pragma unroll
    for (int ks = 0; ks < 8; ++ks) {
      short8 a = *(const short8*)&ldsH[fr * 512 + ((ks * 64 + fq * 16) ^ ((fr & 7) << 4))];
#pragma unroll
      for (int ct = 0; ct < 2; ++ct) {
        int col = (ctb + ct) * 16 + fr;
        az[ct] = __builtin_amdgcn_mfma_f32_16x16x32_bf16(a, wzv[ct][ks], az[ct], 0, 0, 0);
        ar[ct] = __builtin_amdgcn_mfma_f32_16x16x32_bf16(a, wrv[ct][ks], ar[ct], 0, 0, 0);
        short8 wh8 = *(const short8*)&ldsWh[col * 512 + ((ks * 64 + fq * 16) ^ ((col & 7) << 4))];
        ah[ct] = __builtin_amdgcn_mfma_f32_16x16x32_bf16(a, wh8, ah[ct], 0, 0, 0);
      }
    }
    // ---- gates; f32 carry in regs ----
    ushort hnb[8];
#pragma unroll
    for (int ct = 0; ct < 2; ++ct)
#pragma unroll
      for (int ri = 0; ri < 4; ++ri) {
        int idx = ct * 4 + ri;
        f32 zv = fsigmoid(az[ct][ri] + bhz[ct] + bf2f(pz[idx]));
        f32 rv = fsigmoid(ar[ct][ri] + bhr[ct] + bf2f(pr_[idx]));
        f32 hc = ftanh(bf2f(ph[idx]) + rv * (ah[ct][ri] + bhh[ct]));
        f32 hn = zv * hold[idx] + (1.f - zv) * hc;
        hold[idx] = hn;
        hnb[idx] = f2bf(hn);
      }
    __syncthreads();                          // all A-reads of h(t-1) done
    // ---- publish h(t) to ldsH (swizzled scalar writes) ----
#pragma unroll
    for (int ct = 0; ct < 2; ++ct)
#pragma unroll
      for (int ri = 0; ri < 4; ++ri) {
        int col = (ctb + ct) * 16 + fr;
        int r = fq * 4 + ri;
        *(ushort*)&ldsH[r * 512 + ((col * 2) ^ ((r & 7) << 4))] = hnb[ct * 4 + ri];
      }
    __syncthreads();
    // ---- cooperative coalesced hseq store: 512 thr x 16B = 8KB ----
    {
      int r = tid >> 5, kc = tid & 31;
      uint4 v = *(const uint4*)&ldsH[r * 512 + ((kc * 16) ^ ((r & 7) << 4))];
      *(uint4*)&hseq[((size_t)t * 64 + rg4 * 16 + r) * 256 + kc * 8] = v;
    }
  }
}

// ---------------------------------------------------------------------------
// in-place row softmax over 512 bf16, one block per row
__global__ __launch_bounds__(256) void softmax_ip(ushort* __restrict__ p) {
  size_t row = blockIdx.x;
  uint* pr = (uint*)(p + row * 512);
  int tid = threadIdx.x;
  uint u = pr[tid];
  f32 v0 = bf2f((ushort)(u & 0xffff)), v1 = bf2f((ushort)(u >> 16));
  f32 m = fmaxf(v0, v1);
  for (int off = 32; off; off >>= 1) m = fmaxf(m, __shfl_xor(m, off));
  __shared__ f32 red[4];
  __shared__ f32 red2[4];
  if ((tid & 63) == 0) red[tid >> 6] = m;
  __syncthreads();
  m = fmaxf(fmaxf(red[0], red[1]), fmaxf(red[2], red[3]));
  f32 e0 = __expf(v0 - m), e1 = __expf(v1 - m);
  f32 s = e0 + e1;
  for (int off = 32; off; off >>= 1) s += __shfl_xor(s, off);
  if ((tid & 63) == 0) red2[tid >> 6] = s;
  __syncthreads();
  s = red2[0] + red2[1] + red2[2] + red2[3];
  f32 inv = 1.f / s;
  pr[tid] = (uint)f2bf(e0 * inv) | ((uint)f2bf(e1 * inv) << 16);
}

// ---------------------------------------------------------------------------
// CRF log-likelihood, one block (1 wave) per batch element
__global__ __launch_bounds__(64) void crf_ll_k(
    const f32* __restrict__ logits, const int* __restrict__ y,
    const int* __restrict__ seq_len, const f32* __restrict__ trans,
    f32* __restrict__ out) {
  const int b = blockIdx.x, tid = threadIdx.x;
  __shared__ f32 tr[NN][NN];
  __shared__ f32 al[2][NN];
  for (int i = tid; i < NN * NN; i += 64) tr[i / NN][i % NN] = trans[i];
  const f32* em = logits + (size_t)b * TT * NN;
  const int L = seq_len[b];
  if (tid < NN) al[0][tid] = em[tid];
  __syncthreads();
  int cur = 0;
  for (int t = 1; t < TT; ++t) {
    if (t >= L) break;
    if (tid < NN) {
      f32 m = -1e30f;
      for (int i = 0; i < NN; ++i) m = fmaxf(m, al[cur][i] + tr[i][tid]);
      f32 s = 0.f;
      for (int i = 0; i < NN; ++i) s += __expf(al[cur][i] + tr[i][tid] - m);
      al[cur ^ 1][tid] = m + __logf(s) + em[t * NN + tid];
    }
    __syncthreads();
    cur ^= 1;
  }
  f32 us = 0.f, ts = 0.f;
  for (int t = tid; t < TT; t += 64) {
    if (t < L) {
      us += em[t * NN + y[b * TT + t]];
      if (t >= 1) ts += tr[y[b * TT + t - 1]][y[b * TT + t]];
    }
  }
  for (int off = 32; off; off >>= 1) { us += __shfl_xor(us, off); ts += __shfl_xor(ts, off); }
  if (tid == 0) {
    f32 m = -1e30f;
    for (int i = 0; i < NN; ++i) m = fmaxf(m, al[cur][i]);
    f32 s = 0.f;
    for (int i = 0; i < NN; ++i) s += __expf(al[cur][i] - m);
    out[(size_t)BB * TT + b] = us + ts - (m + __logf(s));
  }
}

// CRF Viterbi decode, one block (1 wave) per batch element
__global__ __launch_bounds__(64) void crf_decode_k(
    const f32* __restrict__ logits, const int* __restrict__ seq_len,
    const f32* __restrict__ trans, f32* __restrict__ out) {
  const int b = blockIdx.x, tid = threadIdx.x;
  __shared__ f32 tr[NN][NN];
  __shared__ f32 al[2][NN];
  __shared__ unsigned char bp[TT - 1][NN];
  __shared__ unsigned char pr[TT];
  for (int i = tid; i < NN * NN; i += 64) tr[i / NN][i % NN] = trans[i];
  const f32* em = logits + (size_t)b * TT * NN;
  const int L = seq_len[b];
  if (tid < NN) al[0][tid] = em[tid];
  __syncthreads();
  int cur = 0;
  for (int t = 1; t < TT; ++t) {
    if (tid < NN) {
      if (t < L) {
        f32 m = -1e30f; int arg = 0;
        for (int i = 0; i < NN; ++i) {
          f32 v = al[cur][i] + tr[i][tid];
          if (v > m) { m = v; arg = i; }
        }
        al[cur ^ 1][tid] = m + em[t * NN + tid];
        bp[t - 1][tid] = (unsigned char)arg;
      } else {
        al[cur ^ 1][tid] = al[cur][tid];
        bp[t - 1][tid] = (unsigned char)tid;
      }
    }
    __syncthreads();
    cur ^= 1;
  }
  if (tid == 0) {
    f32 m = -1e30f; int last = 0;
    for (int i = 0; i < NN; ++i)
      if (al[cur][i] > m) { m = al[cur][i]; last = i; }
    int tag = last;
    for (int t = TT - 2; t >= 0; --t) { pr[t + 1] = (unsigned char)tag; tag = bp[t][tag]; }
    pr[0] = (unsigned char)tag;
  }
  __syncthreads();
  for (int t = tid; t < TT; t += 64)
    out[(size_t)b * TT + t] = (f32)pr[t];
}

// ---------------------------------------------------------------------------
extern "C" void kernel_launch(void* const* d_in, const int* in_sizes, int n_in,
                              void* d_out, int out_size, void* d_ws, size_t ws_size,
                              hipStream_t stream) {
  const int* x       = (const int*)d_in[0];
  const int* y       = (const int*)d_in[1];
  const int* seq_len = (const int*)d_in[2];
  const f32* embed   = (const f32*)d_in[3];
  const f32* wx_f    = (const f32*)d_in[4];
  const f32* wh_f    = (const f32*)d_in[5];
  const f32* b_f     = (const f32*)d_in[6];
  const f32* wx_b    = (const f32*)d_in[7];
  const f32* wh_b    = (const f32*)d_in[8];
  const f32* b_b     = (const f32*)d_in[9];
  const f32* wq      = (const f32*)d_in[10];
  const f32* bq      = (const f32*)d_in[11];
  const f32* wk      = (const f32*)d_in[12];
  const f32* bk      = (const f32*)d_in[13];
  const f32* wv      = (const f32*)d_in[14];
  const f32* bv      = (const f32*)d_in[15];
  const f32* wt      = (const f32*)d_in[16];
  const f32* bt      = (const f32*)d_in[17];
  const f32* trans   = (const f32*)d_in[18];
  f32* out = (f32*)d_out;

  char* ws = (char*)d_ws;
  ushort* ebf  = (ushort*)(ws + OFF_EBF);
  ushort* pxfb = (ushort*)(ws + OFF_PXF);
  ushort* pxbb = (ushort*)(ws + OFF_PXB);
  ushort* hfbf = (ushort*)(ws + OFF_HBF_F);
  ushort* hbbf = (ushort*)(ws + OFF_HBF_B);
  ushort* wxtf = (ushort*)(ws + OFF_WXTF);
  ushort* wxtb = (ushort*)(ws + OFF_WXTB);
  ushort* whtf = (ushort*)(ws + OFF_WHTF);
  ushort* whtb = (ushort*)(ws + OFF_WHTB);
  ushort* wqt  = (ushort*)(ws + OFF_WQT);
  ushort* wkt  = (ushort*)(ws + OFF_WKT);
  ushort* wvt  = (ushort*)(ws + OFF_WVT);
  ushort* wtt  = (ushort*)(ws + OFF_WTT);
  ushort* qbf = (ushort*)(ws + OFF_QBF);
  ushort* kbf = (ushort*)(ws + OFF_KBF);
  ushort* vbf = (ushort*)(ws + OFF_VBF);
  ushort* vT  = (ushort*)(ws + OFF_VT);
  ushort* scb = (ushort*)(ws + OFF_SCB);
  ushort* abf = (ushort*)(ws + OFF_ABF);
  f32*    lg  = (f32*)(ws + OFF_LG);

  // ---- setup converts ----
  conv_embed_k<<<8000, 256, 0, stream>>>(embed, ebf, 2048000);
  tconv_k<8><<<768, 256, 0, stream>>>(wx_f, wxtf, 196608, 768);
  tconv_k<8><<<768, 256, 0, stream>>>(wx_b, wxtb, 196608, 768);
  tconv_k<8><<<768, 256, 0, stream>>>(wh_f, whtf, 196608, 768);
  tconv_k<8><<<768, 256, 0, stream>>>(wh_b, whtb, 196608, 768);
  tconv_k<9><<<512, 256, 0, stream>>>(wq, wqt, 131072, 256);
  tconv_k<9><<<512, 256, 0, stream>>>(wk, wkt, 131072, 256);
  tconv_k<9><<<512, 256, 0, stream>>>(wv, wvt, 131072, 256);
  tconv_k<8><<<48, 256, 0, stream>>>(wt, wtt, 12288, 48);

  // ---- px (both dirs), then row-partitioned MFMA scan (no inter-WG sync) ----
  mgemm<GM_PX><<<dim3(6, 256), 256, 0, stream>>>(
      ebf, nullptr, wxtf, nullptr, pxfb, b_f, x, 768, 256, 0);
  mgemm<GM_PX><<<dim3(6, 256), 256, 0, stream>>>(
      ebf, nullptr, wxtb, nullptr, pxbb, b_b, x, 768, 256, 1);
  gru_scan4<<<8, 512, 0, stream>>>(pxfb, pxbb, whtf, whtb, b_f, b_b, hfbf, hbbf);

  // ---- attention + logits, single pass over all 64 batches ----
  mgemm<GM_QKV><<<dim3(2, 256), 256, 0, stream>>>(
      hfbf, hbbf, wqt, nullptr, qbf, bq, nullptr, 256, 512, 0);
  mgemm<GM_QKV><<<dim3(2, 256), 256, 0, stream>>>(
      hfbf, hbbf, wkt, nullptr, kbf, bk, nullptr, 256, 512, 0);
  mgemm<GM_QKV><<<dim3(2, 256), 256, 0, stream>>>(
      hfbf, hbbf, wvt, nullptr, vbf, bv, nullptr, 256, 512, 0);
  tr_v_k<<<dim3(16, 8, 64), 256, 0, stream>>>(vbf, vT);
  mgemm<GM_SC><<<dim3(4, 4, 64), 256, 0, stream>>>(
      qbf, nullptr, kbf, nullptr, scb, nullptr, nullptr, 512, 256, 0);
  softmax_ip<<<BB * TT, 256, 0, stream>>>(scb);
  mgemm<GM_AV><<<dim3(2, 4, 64), 256, 0, stream>>>(
      scb, nullptr, vT, nullptr, abf, nullptr, nullptr, 256, 512, 0);
  mgemm<GM_LG><<<dim3(1, 256), 256, 0, stream>>>(
      abf, nullptr, wtt, lg, nullptr, bt, nullptr, 48, 256, 0);

  // ---- CRF ----
  crf_ll_k<<<BB, 64, 0, stream>>>(lg, y, seq_len, trans, out);
  crf_decode_k<<<BB, 64, 0, stream>>>(lg, seq_len, trans, out);
}

// Round 8
// 2542.153 us; speedup vs baseline: 2.3115x; 1.1420x over previous
//
#include <hip/hip_runtime.h>
#include <math.h>

typedef float f32;
typedef short short8 __attribute__((ext_vector_type(8)));
typedef float f32x4 __attribute__((ext_vector_type(4)));

#define TT 512
#define BB 64
#define DD 256
#define NN 48

// ===== workspace offsets (bytes). Peak ~153.0 MB =====
static const size_t OFF_EBF  = 0;                        // [32000][256] bf16
static const size_t OFF_PXF  = 16384000;                 // [512][64][768] bf16
static const size_t OFF_PXB  = OFF_PXF + 50331648;
static const size_t OFF_HBF_F= OFF_PXB + 50331648;       // [512][64][256] bf16
static const size_t OFF_HBF_B= OFF_HBF_F + 16777216;
static const size_t OFF_WXTF = OFF_HBF_B + 16777216;     // [768][256] bf16
static const size_t OFF_WXTB = OFF_WXTF + 393216;
static const size_t OFF_WHTF = OFF_WXTB + 393216;        // [768][256] bf16 wh^T
static const size_t OFF_WHTB = OFF_WHTF + 393216;
static const size_t OFF_WQT  = OFF_WHTB + 393216;        // [256][512] bf16
static const size_t OFF_WKT  = OFF_WQT + 262144;
static const size_t OFF_WVT  = OFF_WKT + 262144;
static const size_t OFF_WTT  = OFF_WVT + 262144;         // [48][256] bf16
// end 152,985,600
// attn phase aliases the (dead) px arena [16,384,000 .. 117,047,296):
static const size_t OFF_QBF = OFF_PXF;                   // [64][512][256] bf16 (also ABF)
static const size_t OFF_KBF = OFF_QBF + 16777216;        // (also LG f32 after AV)
static const size_t OFF_VBF = OFF_KBF + 16777216;
static const size_t OFF_VT  = OFF_VBF + 16777216;        // [64][256][512] bf16
static const size_t OFF_SCB = OFF_VT  + 16777216;        // [64][512][512] bf16 (in-place SM)
static const size_t OFF_ABF = OFF_QBF;
static const size_t OFF_LG  = OFF_KBF;                   // [64][512][48] f32

__device__ __forceinline__ ushort f2bf(f32 f) {
  union { f32 f; unsigned u; } v; v.f = f;
  unsigned r = v.u + 0x7fffu + ((v.u >> 16) & 1u);   // RNE
  return (ushort)(r >> 16);
}
__device__ __forceinline__ f32 bf2f(ushort u) {
  union { unsigned u; f32 f; } v; v.u = ((unsigned)u) << 16; return v.f;
}
__device__ __forceinline__ f32 fsigmoid(f32 x) { return 1.f / (1.f + __expf(-x)); }
__device__ __forceinline__ f32 ftanh(f32 x) { return 1.f - 2.f / (__expf(2.f * x) + 1.f); }

// ---------------------------------------------------------------------------
// generic transpose+convert: in f32 [P][Q] -> out bf16 [Q][P], P = 1<<PL2
template <int PL2>
__global__ __launch_bounds__(256) void tconv_k(
    const f32* __restrict__ in, ushort* __restrict__ out, int total, int Q) {
  int o = blockIdx.x * 256 + threadIdx.x;
  if (o >= total) return;
  int q = o >> PL2, p = o & ((1 << PL2) - 1);
  out[o] = f2bf(in[(size_t)p * Q + q]);
}

// embed table f32 -> bf16
__global__ __launch_bounds__(256) void conv_embed_k(
    const f32* __restrict__ in, ushort* __restrict__ out, int n4) {
  int i = blockIdx.x * 256 + threadIdx.x;
  if (i >= n4) return;
  float4 v = ((const float4*)in)[i];
  ushort4 o;
  o.x = f2bf(v.x); o.y = f2bf(v.y); o.z = f2bf(v.z); o.w = f2bf(v.w);
  ((ushort4*)out)[i] = o;
}

// v transpose bf16: [64][512][256] -> [64][256][512]
__global__ __launch_bounds__(256) void tr_v_k(
    const ushort* __restrict__ in, ushort* __restrict__ out) {
  __shared__ ushort tile[32][33];
  int b = blockIdx.z;
  int s0 = blockIdx.x * 32, d0 = blockIdx.y * 32;
  int xc = threadIdx.x & 31, y0 = threadIdx.x >> 5;
  for (int yy = y0; yy < 32; yy += 8)
    tile[yy][xc] = in[((size_t)b * 512 + s0 + yy) * 256 + d0 + xc];
  __syncthreads();
  for (int yy = y0; yy < 32; yy += 8)
    out[((size_t)b * 256 + d0 + yy) * 512 + s0 + xc] = tile[xc][yy];
}

// ---------------------------------------------------------------------------
// bf16 MFMA GEMM: 128x128 block tile, BK=32, 256 thr (4 waves, 64x64 each).
enum { GM_PX = 0, GM_QKV = 1, GM_SC = 2, GM_AV = 3, GM_LG = 4 };

template <int MODE>
__global__ __launch_bounds__(256) void mgemm(
    const ushort* __restrict__ Aa, const ushort* __restrict__ Ab,
    const ushort* __restrict__ Bt,
    f32* __restrict__ Cf, ushort* __restrict__ Cb,
    const f32* __restrict__ bias, const int* __restrict__ xi,
    int Ndim, int K, int rev) {
  const int m0 = blockIdx.y * 128;
  const int n0 = blockIdx.x * 128;
  const int bz = blockIdx.z;
  const int tid = threadIdx.x;
  const int l = tid & 63, w = tid >> 6;
  const int wr = w >> 1, wc = w & 1;
  __shared__ __align__(16) short Al[128 * 40];
  __shared__ __align__(16) short Bl[128 * 40];
  f32x4 acc[4][4] = {};

  const int rowa = tid >> 1;
  const int kha = (tid & 1) * 16;
  const int rA = m0 + rowa;
  const ushort* aBase = nullptr;
  const ushort* aBase2 = nullptr;
  if constexpr (MODE == GM_PX) {
    int tg = rA >> 6, b = rA & 63;
    int ts = rev ? (511 - tg) : tg;
    aBase = Aa + (size_t)xi[b * 512 + ts] * 256;
  } else if constexpr (MODE == GM_QKV) {
    int bl = rA >> 9, t = rA & 511;
    aBase = Aa + ((size_t)(t * 64 + bl)) * 256;            // fwd half
    aBase2 = Ab + ((size_t)((511 - t) * 64 + bl)) * 256;   // bwd half
  } else if constexpr (MODE == GM_SC) {
    aBase = Aa + ((size_t)(bz * 512 + rA)) * 256;
  } else if constexpr (MODE == GM_AV) {
    aBase = Aa + ((size_t)(bz * 512 + rA)) * 512;
  } else {
    aBase = Aa + (size_t)rA * 256;
  }
  const int rowb = tid >> 1;
  const int khb = (tid & 1) * 16;
  int rowg = n0 + rowb;
  if constexpr (MODE == GM_SC) rowg += bz * 512;
  if constexpr (MODE == GM_AV) rowg += bz * 256;
  const ushort* bBase = Bt + (size_t)rowg * K;
  const bool bValid = (MODE != GM_LG) || (n0 + rowb < Ndim);

  for (int k0 = 0; k0 < K; k0 += 32) {
    {
      int kk = k0 + kha;
      const ushort* src;
      if constexpr (MODE == GM_QKV)
        src = (kk < 256) ? aBase + kk : aBase2 + (kk - 256);
      else
        src = aBase + kk;
      uint4 a0 = *(const uint4*)src;
      uint4 a1 = *(const uint4*)(src + 8);
      *(uint4*)&Al[rowa * 40 + kha] = a0;
      *(uint4*)&Al[rowa * 40 + kha + 8] = a1;
    }
    {
      uint4 v0 = make_uint4(0, 0, 0, 0), v1 = make_uint4(0, 0, 0, 0);
      if (bValid) {
        const ushort* src = bBase + k0 + khb;
        v0 = *(const uint4*)src;
        v1 = *(const uint4*)(src + 8);
      }
      *(uint4*)&Bl[rowb * 40 + khb] = v0;
      *(uint4*)&Bl[rowb * 40 + khb + 8] = v1;
    }
    __syncthreads();
    const int fr = l & 15, fg = l >> 4;
    short8 af[4], bfr[4];
#pragma unroll
    for (int mf = 0; mf < 4; ++mf)
      af[mf] = *(const short8*)&Al[(wr * 64 + mf * 16 + fr) * 40 + fg * 8];
#pragma unroll
    for (int nf = 0; nf < 4; ++nf)
      bfr[nf] = *(const short8*)&Bl[(wc * 64 + nf * 16 + fr) * 40 + fg * 8];
#pragma unroll
    for (int mf = 0; mf < 4; ++mf)
#pragma unroll
      for (int nf = 0; nf < 4; ++nf)
        acc[mf][nf] = __builtin_amdgcn_mfma_f32_16x16x32_bf16(
            af[mf], bfr[nf], acc[mf][nf], 0, 0, 0);
    __syncthreads();
  }

  const int fr = l & 15, fq = l >> 4;
#pragma unroll
  for (int mf = 0; mf < 4; ++mf) {
#pragma unroll
    for (int nf = 0; nf < 4; ++nf) {
      int col = n0 + wc * 64 + nf * 16 + fr;
      f32 bs = 0.f;
      if (bias && col < Ndim) bs = bias[col];
#pragma unroll
      for (int rg = 0; rg < 4; ++rg) {
        int row = m0 + wr * 64 + mf * 16 + fq * 4 + rg;
        f32 vv = acc[mf][nf][rg] + bs;
        if constexpr (MODE == GM_PX)
          Cb[(size_t)row * 768 + col] = f2bf(vv);
        else if constexpr (MODE == GM_QKV)
          Cb[(size_t)row * 256 + col] = f2bf(vv);
        else if constexpr (MODE == GM_SC)
          Cb[((size_t)bz * 512 + row) * 512 + col] = f2bf(vv);
        else if constexpr (MODE == GM_AV)
          Cb[((size_t)bz * 512 + row) * 256 + col] = f2bf(vv);
        else {
          if (col < Ndim) Cf[(size_t)row * 48 + col] = vv;
        }
      }
    }
  }
}

// ---------------------------------------------------------------------------
// GRU scan v5: pipelined. 8 WGs = 2 dir x 4 row-groups (16 rows), 512 thr.
// Double-buffered ldsH -> ONE barrier/step; px(t+1) prefetched during step t;
// hseq store of h(t) overlapped into step t+1. z/r weights VGPR/AGPR-resident,
// h-gate weights in swizzled LDS. f32 carry in registers.
__global__ __launch_bounds__(512, 1) void gru_scan5(
    const ushort* __restrict__ pxf, const ushort* __restrict__ pxb,
    const ushort* __restrict__ whtf, const ushort* __restrict__ whtb,
    const f32* __restrict__ b_f, const f32* __restrict__ b_b,
    ushort* __restrict__ hfbf, ushort* __restrict__ hbbf) {
  const int dir = blockIdx.x >> 2;
  const int rg4 = blockIdx.x & 3;           // rows rg4*16 .. +15
  const int tid = threadIdx.x;
  const int w = tid >> 6, l = tid & 63;
  const int fr = l & 15, fq = l >> 4;       // fragment row/col, k-group
  const ushort* px  = dir ? pxb : pxf;
  const ushort* wht = dir ? whtb : whtf;
  const f32* bh = (dir ? b_b : b_f) + 768;
  ushort* hseq = dir ? hbbf : hfbf;

  __shared__ __align__(16) char ldsWh[131072];   // h-gate W^T [256 col][256 k] swz
  __shared__ __align__(16) char ldsH[2][8192];   // h double-buffer, swz

  // ---- stage Wh (gate rows 512..767): 8192 x uint4, XOR-swizzled ----
#pragma unroll
  for (int i = 0; i < 16; ++i) {
    int idx = i * 512 + tid;                // 0..8191
    int col = idx >> 5, kc = idx & 31;      // col 0..255, 16B chunk 0..31
    uint4 v = *(const uint4*)&wht[(size_t)(512 + col) * 256 + kc * 8];
    *(uint4*)&ldsWh[col * 512 + ((kc * 16) ^ ((col & 7) << 4))] = v;
  }
  // zero h state buffer 0
  ((uint4*)ldsH[0])[tid] = make_uint4(0, 0, 0, 0);

  const int ctb = w * 2;                    // wave's col-tile base
  // ---- z/r weight fragments -> regs: 2 gates x 2 ct x 8 ks = 128 regs ----
  short8 wzv[2][8], wrv[2][8];
#pragma unroll
  for (int ct = 0; ct < 2; ++ct) {
    int col = (ctb + ct) * 16 + fr;
#pragma unroll
    for (int ks = 0; ks < 8; ++ks) {
      wzv[ct][ks] = *(const short8*)&wht[(size_t)col * 256 + ks * 32 + fq * 8];
      wrv[ct][ks] = *(const short8*)&wht[(size_t)(256 + col) * 256 + ks * 32 + fq * 8];
    }
  }
  f32 bhz[2], bhr[2], bhh[2];
#pragma unroll
  for (int ct = 0; ct < 2; ++ct) {
    int col = (ctb + ct) * 16 + fr;
    bhz[ct] = bh[col]; bhr[ct] = bh[256 + col]; bhh[ct] = bh[512 + col];
  }
  f32 hold[8];
#pragma unroll
  for (int i = 0; i < 8; ++i) hold[i] = 0.f;

  auto loadpx = [&](int t, ushort* pv) {
    const ushort* pxt = px + ((size_t)t * 64 + rg4 * 16) * 768;
#pragma unroll
    for (int ct = 0; ct < 2; ++ct) {
      int col = (ctb + ct) * 16 + fr;
#pragma unroll
      for (int ri = 0; ri < 4; ++ri) {
        const ushort* p = pxt + (fq * 4 + ri) * 768 + col;
        pv[(ct * 4 + ri) * 3 + 0] = p[0];
        pv[(ct * 4 + ri) * 3 + 1] = p[256];
        pv[(ct * 4 + ri) * 3 + 2] = p[512];
      }
    }
  };

  auto step = [&](int t, int buf, const ushort* pc, ushort* pn) {
    // prefetch px(t+1) — consumed next step, a full step of latency cover
    if (t + 1 < TT) loadpx(t + 1, pn);
    // store hseq[t-1] = h(t) from ldsH[buf] (overlaps MFMA; off critical path)
    if (t > 0) {
      int r = tid >> 5, kc = tid & 31;
      uint4 v = *(const uint4*)&ldsH[buf][r * 512 + ((kc * 16) ^ ((r & 7) << 4))];
      *(uint4*)&hseq[((size_t)(t - 1) * 64 + rg4 * 16 + r) * 256 + kc * 8] = v;
    }
    // MFMA: 3 gates x 2 col-tiles, k=256; A streamed from ldsH[buf]
    f32x4 az[2] = {}, ar[2] = {}, ah[2] = {};
#pragma unroll
    for (int ks = 0; ks < 8; ++ks) {
      short8 a = *(const short8*)&ldsH[buf][fr * 512 + ((ks * 64 + fq * 16) ^ ((fr & 7) << 4))];
#pragma unroll
      for (int ct = 0; ct < 2; ++ct) {
        int col = (ctb + ct) * 16 + fr;
        az[ct] = __builtin_amdgcn_mfma_f32_16x16x32_bf16(a, wzv[ct][ks], az[ct], 0, 0, 0);
        ar[ct] = __builtin_amdgcn_mfma_f32_16x16x32_bf16(a, wrv[ct][ks], ar[ct], 0, 0, 0);
        short8 wh8 = *(const short8*)&ldsWh[col * 512 + ((ks * 64 + fq * 16) ^ ((col & 7) << 4))];
        ah[ct] = __builtin_amdgcn_mfma_f32_16x16x32_bf16(a, wh8, ah[ct], 0, 0, 0);
      }
    }
    // gates (f32 carry in regs); publish h(t+1) into ldsH[buf^1]
#pragma unroll
    for (int ct = 0; ct < 2; ++ct)
#pragma unroll
      for (int ri = 0; ri < 4; ++ri) {
        int idx = ct * 4 + ri;
        f32 zv = fsigmoid(az[ct][ri] + bhz[ct] + bf2f(pc[idx * 3 + 0]));
        f32 rv = fsigmoid(ar[ct][ri] + bhr[ct] + bf2f(pc[idx * 3 + 1]));
        f32 hc = ftanh(bf2f(pc[idx * 3 + 2]) + rv * (ah[ct][ri] + bhh[ct]));
        f32 hn = zv * hold[idx] + (1.f - zv) * hc;
        hold[idx] = hn;
        int col = (ctb + ct) * 16 + fr;
        int r = fq * 4 + ri;
        *(ushort*)&ldsH[buf ^ 1][r * 512 + ((col * 2) ^ ((r & 7) << 4))] = f2bf(hn);
      }
    __syncthreads();
  };

  ushort pA[24], pB[24];
  loadpx(0, pA);
  __syncthreads();                          // Wh staged, h0 zeroed
#pragma unroll 1
  for (int t2 = 0; t2 < TT; t2 += 2) {
    step(t2, 0, pA, pB);
    step(t2 + 1, 1, pB, pA);
  }
  // tail: hseq[511] = h(512) sits in ldsH[0]
  {
    int r = tid >> 5, kc = tid & 31;
    uint4 v = *(const uint4*)&ldsH[0][r * 512 + ((kc * 16) ^ ((r & 7) << 4))];
    *(uint4*)&hseq[((size_t)511 * 64 + rg4 * 16 + r) * 256 + kc * 8] = v;
  }
}

// ---------------------------------------------------------------------------
// in-place row softmax over 512 bf16, one block per row
__global__ __launch_bounds__(256) void softmax_ip(ushort* __restrict__ p) {
  size_t row = blockIdx.x;
  uint* pr = (uint*)(p + row * 512);
  int tid = threadIdx.x;
  uint u = pr[tid];
  f32 v0 = bf2f((ushort)(u & 0xffff)), v1 = bf2f((ushort)(u >> 16));
  f32 m = fmaxf(v0, v1);
  for (int off = 32; off; off >>= 1) m = fmaxf(m, __shfl_xor(m, off));
  __shared__ f32 red[4];
  __shared__ f32 red2[4];
  if ((tid & 63) == 0) red[tid >> 6] = m;
  __syncthreads();
  m = fmaxf(fmaxf(red[0], red[1]), fmaxf(red[2], red[3]));
  f32 e0 = __expf(v0 - m), e1 = __expf(v1 - m);
  f32 s = e0 + e1;
  for (int off = 32; off; off >>= 1) s += __shfl_xor(s, off);
  if ((tid & 63) == 0) red2[tid >> 6] = s;
  __syncthreads();
  s = red2[0] + red2[1] + red2[2] + red2[3];
  f32 inv = 1.f / s;
  pr[tid] = (uint)f2bf(e0 * inv) | ((uint)f2bf(e1 * inv) << 16);
}

// ---------------------------------------------------------------------------
// CRF log-likelihood, one block (1 wave) per batch element.
// LSE via exp(trans) matvec: alpha'[j] = M + log(sum_i e^{a_i-M} E_ij) + em[j],
// with E-column j held in 48 loop-invariant registers.
__global__ __launch_bounds__(64) void crf_ll_k(
    const f32* __restrict__ logits, const int* __restrict__ y,
    const int* __restrict__ seq_len, const f32* __restrict__ trans,
    f32* __restrict__ out) {
  const int b = blockIdx.x, tid = threadIdx.x;
  __shared__ f32 tr[NN * NN];
  for (int i = tid; i < NN * NN; i += 64) tr[i] = trans[i];
  const f32* em = logits + (size_t)b * TT * NN;
  const int L = seq_len[b];
  const bool act = tid < NN;
  f32 Ecol[NN];
#pragma unroll
  for (int i = 0; i < NN; ++i)
    Ecol[i] = act ? __expf(trans[i * NN + tid]) : 0.f;
  f32 alpha = act ? em[tid] : -1e30f;
  __syncthreads();
  for (int t = 1; t < L; ++t) {
    f32 m = alpha;
    for (int off = 32; off; off >>= 1) m = fmaxf(m, __shfl_xor(m, off));
    f32 e = __expf(alpha - m);               // inactive lanes -> 0
    f32 s = 0.f;
#pragma unroll
    for (int i = 0; i < NN; ++i) s += __shfl(e, i) * Ecol[i];
    if (act) alpha = m + __logf(s) + em[t * NN + tid];
  }
  f32 us = 0.f, ts = 0.f;
  for (int t = tid; t < TT; t += 64) {
    if (t < L) {
      us += em[t * NN + y[b * TT + t]];
      if (t >= 1) ts += tr[y[b * TT + t - 1] * NN + y[b * TT + t]];
    }
  }
  for (int off = 32; off; off >>= 1) { us += __shfl_xor(us, off); ts += __shfl_xor(ts, off); }
  // final logsumexp over alpha
  f32 m = alpha;
  for (int off = 32; off; off >>= 1) m = fmaxf(m, __shfl_xor(m, off));
  f32 e = __expf(alpha - m);
  f32 s = e;
  for (int off = 32; off; off >>= 1) s += __shfl_xor(s, off);
  if (tid == 0) out[(size_t)BB * TT + b] = us + ts - (m + __logf(s));
}

// CRF Viterbi decode, one block (1 wave) per batch element
__global__ __launch_bounds__(64) void crf_decode_k(
    const f32* __restrict__ logits, const int* __restrict__ seq_len,
    const f32* __restrict__ trans, f32* __restrict__ out) {
  const int b = blockIdx.x, tid = threadIdx.x;
  __shared__ f32 tr[NN][NN];
  __shared__ f32 al[2][NN];
  __shared__ unsigned char bp[TT - 1][NN];
  __shared__ unsigned char pr[TT];
  for (int i = tid; i < NN * NN; i += 64) tr[i / NN][i % NN] = trans[i];
  const f32* em = logits + (size_t)b * TT * NN;
  const int L = seq_len[b];
  if (tid < NN) al[0][tid] = em[tid];
  __syncthreads();
  int cur = 0;
  for (int t = 1; t < TT; ++t) {
    if (tid < NN) {
      if (t < L) {
        f32 m = -1e30f; int arg = 0;
        for (int i = 0; i < NN; ++i) {
          f32 v = al[cur][i] + tr[i][tid];
          if (v > m) { m = v; arg = i; }
        }
        al[cur ^ 1][tid] = m + em[t * NN + tid];
        bp[t - 1][tid] = (unsigned char)arg;
      } else {
        al[cur ^ 1][tid] = al[cur][tid];
        bp[t - 1][tid] = (unsigned char)tid;
      }
    }
    __syncthreads();
    cur ^= 1;
  }
  if (tid == 0) {
    f32 m = -1e30f; int last = 0;
    for (int i = 0; i < NN; ++i)
      if (al[cur][i] > m) { m = al[cur][i]; last = i; }
    int tag = last;
    for (int t = TT - 2; t >= 0; --t) { pr[t + 1] = (unsigned char)tag; tag = bp[t][tag]; }
    pr[0] = (unsigned char)tag;
  }
  __syncthreads();
  for (int t = tid; t < TT; t += 64)
    out[(size_t)b * TT + t] = (f32)pr[t];
}

// ---------------------------------------------------------------------------
extern "C" void kernel_launch(void* const* d_in, const int* in_sizes, int n_in,
                              void* d_out, int out_size, void* d_ws, size_t ws_size,
                              hipStream_t stream) {
  const int* x       = (const int*)d_in[0];
  const int* y       = (const int*)d_in[1];
  const int* seq_len = (const int*)d_in[2];
  const f32* embed   = (const f32*)d_in[3];
  const f32* wx_f    = (const f32*)d_in[4];
  const f32* wh_f    = (const f32*)d_in[5];
  const f32* b_f     = (const f32*)d_in[6];
  const f32* wx_b    = (const f32*)d_in[7];
  const f32* wh_b    = (const f32*)d_in[8];
  const f32* b_b     = (const f32*)d_in[9];
  const f32* wq      = (const f32*)d_in[10];
  const f32* bq      = (const f32*)d_in[11];
  const f32* wk      = (const f32*)d_in[12];
  const f32* bk      = (const f32*)d_in[13];
  const f32* wv      = (const f32*)d_in[14];
  const f32* bv      = (const f32*)d_in[15];
  const f32* wt      = (const f32*)d_in[16];
  const f32* bt      = (const f32*)d_in[17];
  const f32* trans   = (const f32*)d_in[18];
  f32* out = (f32*)d_out;

  char* ws = (char*)d_ws;
  ushort* ebf  = (ushort*)(ws + OFF_EBF);
  ushort* pxfb = (ushort*)(ws + OFF_PXF);
  ushort* pxbb = (ushort*)(ws + OFF_PXB);
  ushort* hfbf = (ushort*)(ws + OFF_HBF_F);
  ushort* hbbf = (ushort*)(ws + OFF_HBF_B);
  ushort* wxtf = (ushort*)(ws + OFF_WXTF);
  ushort* wxtb = (ushort*)(ws + OFF_WXTB);
  ushort* whtf = (ushort*)(ws + OFF_WHTF);
  ushort* whtb = (ushort*)(ws + OFF_WHTB);
  ushort* wqt  = (ushort*)(ws + OFF_WQT);
  ushort* wkt  = (ushort*)(ws + OFF_WKT);
  ushort* wvt  = (ushort*)(ws + OFF_WVT);
  ushort* wtt  = (ushort*)(ws + OFF_WTT);
  ushort* qbf = (ushort*)(ws + OFF_QBF);
  ushort* kbf = (ushort*)(ws + OFF_KBF);
  ushort* vbf = (ushort*)(ws + OFF_VBF);
  ushort* vT  = (ushort*)(ws + OFF_VT);
  ushort* scb = (ushort*)(ws + OFF_SCB);
  ushort* abf = (ushort*)(ws + OFF_ABF);
  f32*    lg  = (f32*)(ws + OFF_LG);

  // ---- setup converts ----
  conv_embed_k<<<8000, 256, 0, stream>>>(embed, ebf, 2048000);
  tconv_k<8><<<768, 256, 0, stream>>>(wx_f, wxtf, 196608, 768);
  tconv_k<8><<<768, 256, 0, stream>>>(wx_b, wxtb, 196608, 768);
  tconv_k<8><<<768, 256, 0, stream>>>(wh_f, whtf, 196608, 768);
  tconv_k<8><<<768, 256, 0, stream>>>(wh_b, whtb, 196608, 768);
  tconv_k<9><<<512, 256, 0, stream>>>(wq, wqt, 131072, 256);
  tconv_k<9><<<512, 256, 0, stream>>>(wk, wkt, 131072, 256);
  tconv_k<9><<<512, 256, 0, stream>>>(wv, wvt, 131072, 256);
  tconv_k<8><<<48, 256, 0, stream>>>(wt, wtt, 12288, 48);

  // ---- px (both dirs), then pipelined row-partitioned MFMA scan ----
  mgemm<GM_PX><<<dim3(6, 256), 256, 0, stream>>>(
      ebf, nullptr, wxtf, nullptr, pxfb, b_f, x, 768, 256, 0);
  mgemm<GM_PX><<<dim3(6, 256), 256, 0, stream>>>(
      ebf, nullptr, wxtb, nullptr, pxbb, b_b, x, 768, 256, 1);
  gru_scan5<<<8, 512, 0, stream>>>(pxfb, pxbb, whtf, whtb, b_f, b_b, hfbf, hbbf);

  // ---- attention + logits, single pass over all 64 batches ----
  mgemm<GM_QKV><<<dim3(2, 256), 256, 0, stream>>>(
      hfbf, hbbf, wqt, nullptr, qbf, bq, nullptr, 256, 512, 0);
  mgemm<GM_QKV><<<dim3(2, 256), 256, 0, stream>>>(
      hfbf, hbbf, wkt, nullptr, kbf, bk, nullptr, 256, 512, 0);
  mgemm<GM_QKV><<<dim3(2, 256), 256, 0, stream>>>(
      hfbf, hbbf, wvt, nullptr, vbf, bv, nullptr, 256, 512, 0);
  tr_v_k<<<dim3(16, 8, 64), 256, 0, stream>>>(vbf, vT);
  mgemm<GM_SC><<<dim3(4, 4, 64), 256, 0, stream>>>(
      qbf, nullptr, kbf, nullptr, scb, nullptr, nullptr, 512, 256, 0);
  softmax_ip<<<BB * TT, 256, 0, stream>>>(scb);
  mgemm<GM_AV><<<dim3(2, 4, 64), 256, 0, stream>>>(
      scb, nullptr, vT, nullptr, abf, nullptr, nullptr, 256, 512, 0);
  mgemm<GM_LG><<<dim3(1, 256), 256, 0, stream>>>(
      abf, nullptr, wtt, lg, nullptr, bt, nullptr, 48, 256, 0);

  // ---- CRF ----
  crf_ll_k<<<BB, 64, 0, stream>>>(lg, y, seq_len, trans, out);
  crf_decode_k<<<BB, 64, 0, stream>>>(lg, seq_len, trans, out);
}